// Round 10
// baseline (168.814 us; speedup 1.0000x reference)
//
#include <hip/hip_runtime.h>
#include <cstddef>

#define NB 8
#define NT 2048
#define NE 256
#define NH 4
#define ND 64
#define NP 8

typedef short bf16x8 __attribute__((ext_vector_type(8)));
typedef float f32x4 __attribute__((ext_vector_type(4)));

__device__ __forceinline__ unsigned short f2bf(float f) {
  unsigned u = __builtin_bit_cast(unsigned, f);
  u += 0x7fffu + ((u >> 16) & 1u);          // RNE
  return (unsigned short)(u >> 16);
}
__device__ __forceinline__ float bf2f(unsigned short h) {
  unsigned u = ((unsigned)h) << 16;
  return __builtin_bit_cast(float, u);
}
// packed hi/lo split of a float pair (integer-only)
__device__ __forceinline__ void split2(float a, float b, unsigned& hi, unsigned& lo) {
  const unsigned short ha = f2bf(a), hb = f2bf(b);
  hi = (unsigned)ha | ((unsigned)hb << 16);
  const unsigned short la = f2bf(a - bf2f(ha));
  const unsigned short lb = f2bf(b - bf2f(hb));
  lo = (unsigned)la | ((unsigned)lb << 16);
}
__device__ __forceinline__ void gld16(const void* g, void* l) {
  __builtin_amdgcn_global_load_lds((const __attribute__((address_space(1))) unsigned*)g,
                                   (__attribute__((address_space(3))) unsigned*)l, 16, 0, 0);
}

// q-prescale: 1/8 (attn scale) * log2(e) (exp2 domain for softmax)
#define QSC 0.180336880111120419f

// ---------------- setup: wqk split(+q prescale), w_in split, prep(uv->wqkv rows), zero --
__global__ __launch_bounds__(256) void setup_kernel(
    const float* __restrict__ w_in, const float* __restrict__ w_q,
    const float* __restrict__ w_k, const float* __restrict__ b_q,
    const float* __restrict__ b_k, const float* __restrict__ w_o,
    const float* __restrict__ b_o, const float* __restrict__ w_bd,
    const float* __restrict__ b_bd, const float* __restrict__ w_v,
    const float* __restrict__ b_v,
    unsigned short* __restrict__ wihi, unsigned short* __restrict__ wilo,
    unsigned short* __restrict__ wqkvhi, unsigned short* __restrict__ wqkvlo,
    float* __restrict__ bqk, float* __restrict__ consts, float* __restrict__ psum)
{
  __shared__ float wbd_s[NE];
  __shared__ float u_s[NE];
  const int b = blockIdx.x, tid = threadIdx.x;
  if (b < 512) {
    const int i = b * 256 + tid;                         // [0,131072)
    const float v = (i < 65536) ? w_q[i] * QSC : w_k[i - 65536];
    const unsigned short h = f2bf(v);
    wqkvhi[i] = h;
    wqkvlo[i] = f2bf(v - bf2f(h));
    if (i < 512) bqk[i] = (i < 256) ? b_q[i] * QSC : b_k[i - 256];
  } else if (b < 576) {
    const int i = (b - 512) * 256 + tid;                 // float4 idx [0,16384)
    const float4 v = *(const float4*)(w_in + (size_t)i * 4);
    const float vv[4] = {v.x, v.y, v.z, v.w};
    unsigned short h4[4], l4[4];
    #pragma unroll
    for (int j = 0; j < 4; ++j) {
      h4[j] = f2bf(vv[j]);
      l4[j] = f2bf(vv[j] - bf2f(h4[j]));
    }
    *(ushort2*)(wihi + (size_t)i * 4)     = make_ushort2(h4[0], h4[1]);
    *(ushort2*)(wihi + (size_t)i * 4 + 2) = make_ushort2(h4[2], h4[3]);
    *(ushort2*)(wilo + (size_t)i * 4)     = make_ushort2(l4[0], l4[1]);
    *(ushort2*)(wilo + (size_t)i * 4 + 2) = make_ushort2(l4[2], l4[3]);
  } else if (b == 576) {
    wbd_s[tid] = w_bd[tid];
    __syncthreads();
    float a = 0.f;
    for (int j = 0; j < NE; ++j) a = fmaf(wbd_s[j], w_o[j * NE + tid], a);
    u_s[tid] = a;
    __syncthreads();
    #pragma unroll
    for (int hh = 0; hh < NH; ++hh) {
      float a2 = 0.f;
      for (int d = 0; d < ND; ++d)
        a2 = fmaf(u_s[hh * ND + d], w_v[(size_t)(hh * ND + d) * NE + tid], a2);
      const unsigned short hb = f2bf(a2);
      wqkvhi[(512 + hh) * 256 + tid] = hb;
      wqkvlo[(512 + hh) * 256 + tid] = f2bf(a2 - bf2f(hb));
    }
    for (int i = tid; i < 60 * 256; i += 256) {          // zero-pad rows 516..575
      wqkvhi[516 * 256 + i] = 0;
      wqkvlo[516 * 256 + i] = 0;
    }
    if (tid == 0) {
      float cc = 0.f;
      for (int j = 0; j < NE; ++j) cc = fmaf(wbd_s[j], b_o[j], cc);
      consts[0] = cc + b_bd[0];
    }
    if (tid < 4) {
      float cv = 0.f;
      for (int d = 0; d < ND; ++d) cv = fmaf(u_s[tid * ND + d], b_v[tid * ND + d], cv);
      bqk[512 + tid] = cv;
    } else if (tid < 64) {
      bqk[512 + tid] = 0.f;
    }
  } else {
    for (int i = tid; i < NB * NP * NE; i += 256) psum[i] = 0.f;
  }
}

// ---------------- hgemm v2: LDS-staged, dbuf, gld16. h = x @ w_in^T + b_in -------------
__global__ __launch_bounds__(256) void hgemm_kernel(
    const float* __restrict__ x,
    const unsigned short* __restrict__ wihi, const unsigned short* __restrict__ wilo,
    const float* __restrict__ b_in,
    unsigned short* __restrict__ hhi, unsigned short* __restrict__ hlo)
{
  __shared__ __align__(16) char sm[2][24576];
  const int tid = threadIdx.x;
  const int wave = tid >> 6, lane = tid & 63;
  const int lr = lane & 15, lg = lane >> 4;
  const int wm = wave >> 1, wn = wave & 1;
  const int bid = blockIdx.x;
  const int idx = bid >> 3;
  const int m0 = ((bid & 7) * 16 + (idx >> 2)) * 128;
  const int n0 = (idx & 3) * 64;

  const float* aSrc[4];
  #pragma unroll
  for (int c = 0; c < 4; ++c) {
    const int L = c * 4096 + tid * 16;
    const int row = L >> 7, w = (L >> 4) & 7;
    aSrc[c] = x + (size_t)(m0 + row) * 256 + (w ^ (row & 7)) * 4;
  }
  const unsigned short* wSrc[2];
  #pragma unroll
  for (int c = 0; c < 2; ++c) {
    const int L = c * 4096 + tid * 16;
    const int half = (L >> 12) & 1;
    const int Lh = L & 4095;
    const int col = Lh >> 6, w = (Lh >> 4) & 3;
    wSrc[c] = (half ? wilo : wihi) + (size_t)(n0 + col) * 256 + (w ^ ((col >> 1) & 3)) * 8;
  }
  int aoff[4][2], woff[2];
  #pragma unroll
  for (int s = 0; s < 4; ++s) {
    const int row = wm * 64 + s * 16 + lr;
    const int b0 = row * 128 + lg * 32;
    const int f = (row & 7) << 4;
    aoff[s][0] = b0 ^ f;
    aoff[s][1] = (b0 + 16) ^ f;
  }
  #pragma unroll
  for (int ns = 0; ns < 2; ++ns) {
    const int col = wn * 32 + ns * 16 + lr;
    woff[ns] = (col * 64 + lg * 16) ^ (((col >> 1) & 3) << 4);
  }

  f32x4 acc[4][2];
  #pragma unroll
  for (int s = 0; s < 4; ++s)
    #pragma unroll
    for (int ns = 0; ns < 2; ++ns) acc[s][ns] = (f32x4){0.f, 0.f, 0.f, 0.f};

  {
    char* lb = sm[0];
    #pragma unroll
    for (int c = 0; c < 4; ++c) gld16(aSrc[c], lb + c * 4096 + wave * 1024);
    #pragma unroll
    for (int c = 0; c < 2; ++c) gld16(wSrc[c], lb + 16384 + c * 4096 + wave * 1024);
  }

  for (int kt = 0; kt < 8; ++kt) {
    __syncthreads();
    if (kt < 7) {
      char* nb = sm[(kt + 1) & 1];
      #pragma unroll
      for (int c = 0; c < 4; ++c) gld16(aSrc[c] + (kt + 1) * 32, nb + c * 4096 + wave * 1024);
      #pragma unroll
      for (int c = 0; c < 2; ++c) gld16(wSrc[c] + (kt + 1) * 32, nb + 16384 + c * 4096 + wave * 1024);
    }
    const char* lb = sm[kt & 1];
    bf16x8 ah[4], al[4], wh[2], wl[2];
    #pragma unroll
    for (int s = 0; s < 4; ++s) {
      const f32x4 p0 = *(const f32x4*)(lb + aoff[s][0]);
      const f32x4 p1 = *(const f32x4*)(lb + aoff[s][1]);
      unsigned h0, h1, h2, h3, l0, l1, l2, l3;
      split2(p0[0], p0[1], h0, l0);
      split2(p0[2], p0[3], h1, l1);
      split2(p1[0], p1[1], h2, l2);
      split2(p1[2], p1[3], h3, l3);
      const uint4 hu = make_uint4(h0, h1, h2, h3);
      const uint4 lu = make_uint4(l0, l1, l2, l3);
      ah[s] = __builtin_bit_cast(bf16x8, hu);
      al[s] = __builtin_bit_cast(bf16x8, lu);
    }
    #pragma unroll
    for (int ns = 0; ns < 2; ++ns) {
      wh[ns] = *(const bf16x8*)(lb + 16384 + woff[ns]);
      wl[ns] = *(const bf16x8*)(lb + 20480 + woff[ns]);
    }
    #pragma unroll
    for (int s = 0; s < 4; ++s)
      #pragma unroll
      for (int ns = 0; ns < 2; ++ns) {
        acc[s][ns] = __builtin_amdgcn_mfma_f32_16x16x32_bf16(ah[s], wh[ns], acc[s][ns], 0, 0, 0);
        acc[s][ns] = __builtin_amdgcn_mfma_f32_16x16x32_bf16(ah[s], wl[ns], acc[s][ns], 0, 0, 0);
        acc[s][ns] = __builtin_amdgcn_mfma_f32_16x16x32_bf16(al[s], wh[ns], acc[s][ns], 0, 0, 0);
      }
  }
  #pragma unroll
  for (int s = 0; s < 4; ++s)
    #pragma unroll
    for (int ns = 0; ns < 2; ++ns)
      #pragma unroll
      for (int reg = 0; reg < 4; ++reg) {
        const int row = m0 + wm * 64 + s * 16 + lg * 4 + reg;
        const int col = n0 + wn * 32 + ns * 16 + lr;
        const float v = acc[s][ns][reg] + b_in[col];
        const size_t i2 = (size_t)row * 256 + col;
        const unsigned short hb = f2bf(v);
        hhi[i2] = hb;
        hlo[i2] = f2bf(v - bf2f(hb));
      }
}

// ---------------- qkv-gemm v2: LDS-staged dbuf. [q*QSC|k|vu] = h @ wqkv^T + bqk --------
__global__ __launch_bounds__(256) void qkvgemm_kernel(
    const unsigned short* __restrict__ Ahi, const unsigned short* __restrict__ Alo,
    const unsigned short* __restrict__ Whi, const unsigned short* __restrict__ Wlo,
    const float* __restrict__ bias,
    unsigned short* __restrict__ Qhi, unsigned short* __restrict__ Qlo,
    unsigned short* __restrict__ Khi, unsigned short* __restrict__ Klo,
    float* __restrict__ vubuf)
{
  __shared__ __align__(16) char sm[2][24576];
  const int tid = threadIdx.x;
  const int wave = tid >> 6, lane = tid & 63;
  const int lr = lane & 15, lg = lane >> 4;
  const int wm = wave >> 1, wn = wave & 1;
  const int bid = blockIdx.x;
  const int idx = bid >> 3;                     // 0..143
  const int m0 = ((bid & 7) * 16 + idx / 9) * 128;
  const int n0 = (idx % 9) * 64;

  const unsigned short* aSrc[4];
  #pragma unroll
  for (int c = 0; c < 4; ++c) {
    const int L = c * 4096 + tid * 16;
    const int half = L >> 13;
    const int Lh = L & 8191;
    const int row = Lh >> 6, w = (Lh >> 4) & 3;
    aSrc[c] = (half ? Alo : Ahi) + (size_t)(m0 + row) * 256 + (w ^ ((row >> 1) & 3)) * 8;
  }
  const unsigned short* wSrc[2];
  #pragma unroll
  for (int c = 0; c < 2; ++c) {
    const int L = c * 4096 + tid * 16;
    const int half = (L >> 12) & 1;
    const int Lh = L & 4095;
    const int col = Lh >> 6, w = (Lh >> 4) & 3;
    wSrc[c] = (half ? Wlo : Whi) + (size_t)(n0 + col) * 256 + (w ^ ((col >> 1) & 3)) * 8;
  }
  int aoff[4], woff[2];
  #pragma unroll
  for (int s = 0; s < 4; ++s) {
    const int row = wm * 64 + s * 16 + lr;
    aoff[s] = (row * 64 + lg * 16) ^ (((row >> 1) & 3) << 4);
  }
  #pragma unroll
  for (int ns = 0; ns < 2; ++ns) {
    const int col = wn * 32 + ns * 16 + lr;
    woff[ns] = (col * 64 + lg * 16) ^ (((col >> 1) & 3) << 4);
  }

  f32x4 acc[4][2];
  #pragma unroll
  for (int s = 0; s < 4; ++s)
    #pragma unroll
    for (int ns = 0; ns < 2; ++ns) acc[s][ns] = (f32x4){0.f, 0.f, 0.f, 0.f};

  {
    char* lb = sm[0];
    #pragma unroll
    for (int c = 0; c < 4; ++c) gld16(aSrc[c], lb + c * 4096 + wave * 1024);
    #pragma unroll
    for (int c = 0; c < 2; ++c) gld16(wSrc[c], lb + 16384 + c * 4096 + wave * 1024);
  }

  for (int kt = 0; kt < 8; ++kt) {
    __syncthreads();
    if (kt < 7) {
      char* nb = sm[(kt + 1) & 1];
      #pragma unroll
      for (int c = 0; c < 4; ++c) gld16(aSrc[c] + (kt + 1) * 32, nb + c * 4096 + wave * 1024);
      #pragma unroll
      for (int c = 0; c < 2; ++c) gld16(wSrc[c] + (kt + 1) * 32, nb + 16384 + c * 4096 + wave * 1024);
    }
    const char* lb = sm[kt & 1];
    bf16x8 ah[4], al[4], wh[2], wl[2];
    #pragma unroll
    for (int s = 0; s < 4; ++s) {
      ah[s] = *(const bf16x8*)(lb + aoff[s]);
      al[s] = *(const bf16x8*)(lb + 8192 + aoff[s]);
    }
    #pragma unroll
    for (int ns = 0; ns < 2; ++ns) {
      wh[ns] = *(const bf16x8*)(lb + 16384 + woff[ns]);
      wl[ns] = *(const bf16x8*)(lb + 20480 + woff[ns]);
    }
    #pragma unroll
    for (int s = 0; s < 4; ++s)
      #pragma unroll
      for (int ns = 0; ns < 2; ++ns) {
        acc[s][ns] = __builtin_amdgcn_mfma_f32_16x16x32_bf16(ah[s], wh[ns], acc[s][ns], 0, 0, 0);
        acc[s][ns] = __builtin_amdgcn_mfma_f32_16x16x32_bf16(ah[s], wl[ns], acc[s][ns], 0, 0, 0);
        acc[s][ns] = __builtin_amdgcn_mfma_f32_16x16x32_bf16(al[s], wh[ns], acc[s][ns], 0, 0, 0);
      }
  }
  #pragma unroll
  for (int s = 0; s < 4; ++s)
    #pragma unroll
    for (int ns = 0; ns < 2; ++ns)
      #pragma unroll
      for (int reg = 0; reg < 4; ++reg) {
        const int row = m0 + wm * 64 + s * 16 + lg * 4 + reg;
        const int col = n0 + wn * 32 + ns * 16 + lr;
        const float v = acc[s][ns][reg] + bias[col];
        const int b = row >> 11, t = row & 2047;
        if (col < 512) {
          const int c = col & 255;
          const int head = c >> 6, d = c & 63;
          const size_t i2 = (((size_t)(b * NH + head)) * NT + t) * ND + d;
          const unsigned short hb = f2bf(v);
          if (col < 256) { Qhi[i2] = hb; Qlo[i2] = f2bf(v - bf2f(hb)); }
          else           { Khi[i2] = hb; Klo[i2] = f2bf(v - bf2f(hb)); }
        } else if (col < 516) {
          vubuf[((size_t)(b * NH + (col - 512))) * NT + t] = v;
        }
      }
}

// ---------------- attention v7: high-occupancy stage-once, split-K x16 -----------------
// 8192 blocks; block = 128 q-rows x 128 k-rows (2 tiles staged upfront, 1 barrier).
// 512 thr / 8 waves; wave = 16 q-rows. 33KB LDS -> 4 blocks/CU. exp2-domain softmax.
__global__ __launch_bounds__(512, 6) void attn_kernel7(
    const unsigned short* __restrict__ qhi, const unsigned short* __restrict__ qlo,
    const unsigned short* __restrict__ khi, const unsigned short* __restrict__ klo,
    const float* __restrict__ vu, float2* __restrict__ part2)
{
  __shared__ __align__(16) char kbuf[2][16384];   // 2 tiles x [hi 8KB | lo 8KB], swizzled
  __shared__ float vu_s[128];
  const int tid = threadIdx.x;
  const int wave = tid >> 6, lane = tid & 63;
  const int lr = lane & 15, lg = lane >> 4;
  // XCD-aware: bid&7 -> XCD; each XCD covers 4 contiguous bh (K/Q L2-resident)
  const int bid = blockIdx.x;                     // 0..8191
  const int idx = bid >> 3;                       // 0..1023
  const int bh = (bid & 7) * 4 + (idx >> 8);
  const int rem = idx & 255;
  const int qt = rem >> 4, kh = rem & 15;
  const size_t base = (size_t)bh * NT * ND;
  const int qrow0 = qt * 128 + wave * 16;
  const int krow0 = kh * 128;

  if (tid < 128) vu_s[tid] = vu[(size_t)bh * NT + krow0 + tid];

  // Q fragments in regs: [d-slice][hi/lo]
  bf16x8 qf[2][2];
  #pragma unroll
  for (int ds = 0; ds < 2; ++ds) {
    const size_t off = base + (size_t)(qrow0 + lr) * ND + ds * 32 + lg * 8;
    qf[ds][0] = *(const bf16x8*)(qhi + off);
    qf[ds][1] = *(const bf16x8*)(qlo + off);
  }

  // pre-swizzled global source offset (involution; LDS dest linear per lane)
  const int so = (tid * 16) ^ (((tid >> 3) & 7) << 4);
  int ro0[4], ro1[4];
  #pragma unroll
  for (int ns = 0; ns < 4; ++ns) {
    const int r = ns * 16 + lr;
    const int sw = (r & 7) << 4;
    const int ob = r * 128 + lg * 16;
    ro0[ns] = ob ^ sw;
    ro1[ns] = (ob + 64) ^ sw;
  }
  const char* srcH = (const char*)(khi + base + (size_t)krow0 * ND);
  const char* srcL = (const char*)(klo + base + (size_t)krow0 * ND);
  // stage BOTH tiles via async DMA, one barrier total
  #pragma unroll
  for (int t = 0; t < 2; ++t) {
    gld16(srcH + t * 8192 + so, &kbuf[t][wave * 1024]);
    gld16(srcL + t * 8192 + so, &kbuf[t][8192 + wave * 1024]);
  }
  __syncthreads();                                // drains all gld16; only barrier

  float l[4], sv[4];
  #pragma unroll
  for (int i = 0; i < 4; ++i) { l[i] = 0.f; sv[i] = 0.f; }
  const f32x4 Z = (f32x4){0.f, 0.f, 0.f, 0.f};    // persistent zero C-operand

  #pragma unroll
  for (int kt = 0; kt < 2; ++kt) {
    const char* kb = (const char*)kbuf[kt];
    f32x4 acc[4];
    float vuv[4];
    __builtin_amdgcn_s_setprio(1);
    #pragma unroll
    for (int ns = 0; ns < 4; ++ns) {
      const bf16x8 kh0 = *(const bf16x8*)(kb + ro0[ns]);
      const bf16x8 kh1 = *(const bf16x8*)(kb + ro1[ns]);
      const bf16x8 kl0 = *(const bf16x8*)(kb + 8192 + ro0[ns]);
      const bf16x8 kl1 = *(const bf16x8*)(kb + 8192 + ro1[ns]);
      vuv[ns] = vu_s[kt * 64 + ns * 16 + lr];
      acc[ns] = __builtin_amdgcn_mfma_f32_16x16x32_bf16(qf[0][0], kh0, Z, 0, 0, 0);
      acc[ns] = __builtin_amdgcn_mfma_f32_16x16x32_bf16(qf[0][0], kl0, acc[ns], 0, 0, 0);
      acc[ns] = __builtin_amdgcn_mfma_f32_16x16x32_bf16(qf[0][1], kh0, acc[ns], 0, 0, 0);
      acc[ns] = __builtin_amdgcn_mfma_f32_16x16x32_bf16(qf[1][0], kh1, acc[ns], 0, 0, 0);
      acc[ns] = __builtin_amdgcn_mfma_f32_16x16x32_bf16(qf[1][0], kl1, acc[ns], 0, 0, 0);
      acc[ns] = __builtin_amdgcn_mfma_f32_16x16x32_bf16(qf[1][1], kh1, acc[ns], 0, 0, 0);
    }
    __builtin_amdgcn_s_setprio(0);
    // exp2-domain softmax accumulation (scores already in log2 units via QSC)
    #pragma unroll
    for (int reg = 0; reg < 4; ++reg)
      #pragma unroll
      for (int ns = 0; ns < 4; ++ns) {
        const float e = __builtin_amdgcn_exp2f(acc[ns][reg]);
        l[reg] += e;
        sv[reg] = fmaf(e, vuv[ns], sv[reg]);
      }
  }
  // reduce partial l/sv across the 16-lane column group
  #pragma unroll
  for (int reg = 0; reg < 4; ++reg) {
    #pragma unroll
    for (int off = 1; off < 16; off <<= 1) {
      l[reg]  += __shfl_xor(l[reg],  off, 16);
      sv[reg] += __shfl_xor(sv[reg], off, 16);
    }
  }
  if (lr == 0) {
    #pragma unroll
    for (int reg = 0; reg < 4; ++reg) {
      const int row = qrow0 + lg * 4 + reg;
      part2[(((size_t)bh * NT + row) << 4) + kh] = make_float2(l[reg], sv[reg]);
    }
  }
}

// ---------------- combine: reduce split-K x16 partials -> bs = sigmoid(logit) ----------
// grid 64 x 256: one thread per (b,t). Reads 4hh x 16 pairs (512B), coalesced per hh.
__global__ __launch_bounds__(256) void combine_kernel(
    const float4* __restrict__ part4, const float* __restrict__ consts,
    float* __restrict__ bs)
{
  const int gid = blockIdx.x * 256 + threadIdx.x;    // 0..16383
  const int b = gid >> 11, t = gid & 2047;
  float logit = consts[0];
  #pragma unroll
  for (int hh = 0; hh < NH; ++hh) {
    const size_t p0 = ((size_t)((b * NH + hh) * NT) + t) * 8;   // 8 float4 = 16 {l,sv}
    float lsum = 0.f, ssum = 0.f;
    #pragma unroll
    for (int q = 0; q < 8; ++q) {
      const float4 p = part4[p0 + q];
      lsum += p.x + p.z;
      ssum += p.y + p.w;
    }
    logit += ssum / lsum;
  }
  bs[gid] = 1.f / (1.f + expf(-logit));
}

// ---------------- boundary: cumsum bs, pid, counts (one block per batch) ---------------
__global__ __launch_bounds__(256) void boundary_kernel(
    const float* __restrict__ bs, int* __restrict__ pid, int* __restrict__ counts)
{
  const int b = blockIdx.x, tid = threadIdx.x;
  __shared__ float partial[256];
  __shared__ int cnt_s[8];
  float v[8];
  float run = 0.f;
  const float4 b0 = *(const float4*)(bs + b * NT + tid * 8);
  const float4 b1 = *(const float4*)(bs + b * NT + tid * 8 + 4);
  const float bv[8] = {b0.x, b0.y, b0.z, b0.w, b1.x, b1.y, b1.z, b1.w};
  #pragma unroll
  for (int i = 0; i < 8; ++i) { run += bv[i]; v[i] = run; }
  float x = run;
  partial[tid] = x;
  __syncthreads();
  for (int off = 1; off < 256; off <<= 1) {
    const float y = (tid >= off) ? partial[tid - off] : 0.f;
    __syncthreads();
    x += y;
    partial[tid] = x;
    __syncthreads();
  }
  const float total = partial[255];
  if (tid < 8) cnt_s[tid] = 0;
  __syncthreads();
  const float denom = fmaxf(total, 1e-6f);
  const float excl = x - run;
  #pragma unroll
  for (int i = 0; i < 8; ++i) {
    const float norm = (excl + v[i]) / denom;
    int pp = (int)(norm * 8.f);
    pp = pp > 7 ? 7 : pp;
    pid[b * NT + tid * 8 + i] = pp;
    atomicAdd(&cnt_s[pp], 1);
  }
  __syncthreads();
  if (tid < 8) counts[b * 8 + tid] = cnt_s[tid];
}

// ---------------- pool hhi into patch sums (branchless 8-way select) -------------------
__global__ __launch_bounds__(256) void pool_kernel(
    const unsigned short* __restrict__ hhi, const int* __restrict__ pid,
    float* __restrict__ psum)
{
  const int b = blockIdx.x >> 4, chunk = blockIdx.x & 15;
  const int tid = threadIdx.x;
  __shared__ int pid_s[128];
  const int t0 = chunk * 128;
  if (tid < 128) pid_s[tid] = pid[b * NT + t0 + tid];
  __syncthreads();
  float acc[8] = {};
  for (int tok = 0; tok < 128; ++tok) {
    const float val = bf2f(hhi[((size_t)b * NT + t0 + tok) * NE + tid]);
    const int p = pid_s[tok];
    #pragma unroll
    for (int pp = 0; pp < 8; ++pp) acc[pp] += (p == pp) ? val : 0.f;
  }
  #pragma unroll
  for (int pp = 0; pp < 8; ++pp)
    atomicAdd(&psum[((size_t)b * NP + pp) * NE + tid], acc[pp]);
}

// ---------------- final: out = (psum/count) @ w_pr^T + b_pr ---------------------------
__global__ __launch_bounds__(256) void final_kernel(
    const float* __restrict__ psum, const int* __restrict__ counts,
    const float* __restrict__ w_pr, const float* __restrict__ b_pr, float* __restrict__ out)
{
  const int bp = blockIdx.x;
  const int tid = threadIdx.x;
  __shared__ float pe[NE];
  const float cnt = fmaxf((float)counts[bp], 1.f);
  pe[tid] = psum[(size_t)bp * NE + tid] / cnt;
  __syncthreads();
  float acc = 0.f;
  for (int e = 0; e < NE; ++e) acc = fmaf(pe[e], w_pr[(size_t)tid * NE + e], acc);
  out[(size_t)bp * NE + tid] = acc + b_pr[tid];
}

extern "C" void kernel_launch(void* const* d_in, const int* in_sizes, int n_in,
                              void* d_out, int out_size, void* d_ws, size_t ws_size,
                              hipStream_t stream) {
  (void)in_sizes; (void)n_in; (void)out_size; (void)ws_size;
  const float* x    = (const float*)d_in[0];
  const float* w_in = (const float*)d_in[1];
  const float* b_in = (const float*)d_in[2];
  const float* w_q  = (const float*)d_in[3];
  const float* b_q  = (const float*)d_in[4];
  const float* w_k  = (const float*)d_in[5];
  const float* b_k  = (const float*)d_in[6];
  const float* w_v  = (const float*)d_in[7];
  const float* b_v  = (const float*)d_in[8];
  const float* w_o  = (const float*)d_in[9];
  const float* b_o  = (const float*)d_in[10];
  const float* w_bd = (const float*)d_in[11];
  const float* b_bd = (const float*)d_in[12];
  const float* w_pr = (const float*)d_in[13];
  const float* b_pr = (const float*)d_in[14];
  float* out = (float*)d_out;

  const size_t M = (size_t)NB * NT;                       // 16384
  unsigned short* hhi = (unsigned short*)d_ws;            // M*NE u16 each
  unsigned short* hlo = hhi + M * NE;
  unsigned short* qhi = hlo + M * NE;
  unsigned short* qlo = qhi + M * NE;
  unsigned short* khi = qlo + M * NE;
  unsigned short* klo = khi + M * NE;
  unsigned short* wihi = klo + M * NE;                    // 65,536 each
  unsigned short* wilo = wihi + 65536;
  unsigned short* wqkvhi = wilo + 65536;                  // 147,456 each (576x256)
  unsigned short* wqkvlo = wqkvhi + 147456;
  float* bqk    = (float*)(wqkvlo + 147456);              // 576
  float* vubuf  = bqk + 576;                              // 65,536 [B,H,T]
  float* part   = vubuf + 65536;                          // 2,097,152 [bh][t][kh16][{l,sv}]
  float* bsbuf  = part + 2097152;                         // 16,384
  float* consts = bsbuf + 16384;                          // 8
  float* psum   = consts + 8;                             // 16,384
  int*   pid    = (int*)(psum + 16384);                   // 16,384
  int*   counts = pid + 16384;                            // 64

  setup_kernel<<<578, 256, 0, stream>>>(w_in, w_q, w_k, b_q, b_k, w_o, b_o,
      w_bd, b_bd, w_v, b_v, wihi, wilo, wqkvhi, wqkvlo, bqk, consts, psum);
  hgemm_kernel<<<512, 256, 0, stream>>>(x, wihi, wilo, b_in, hhi, hlo);
  qkvgemm_kernel<<<1152, 256, 0, stream>>>(hhi, hlo, wqkvhi, wqkvlo, bqk,
      qhi, qlo, khi, klo, vubuf);
  attn_kernel7<<<8192, 512, 0, stream>>>(qhi, qlo, khi, klo, vubuf, (float2*)part);
  combine_kernel<<<64, 256, 0, stream>>>((const float4*)part, consts, bsbuf);
  boundary_kernel<<<8, 256, 0, stream>>>(bsbuf, pid, counts);
  pool_kernel<<<128, 256, 0, stream>>>(hhi, pid, psum);
  final_kernel<<<64, 256, 0, stream>>>(psum, counts, w_pr, b_pr, out);
}

// Round 11
// 153.952 us; speedup vs baseline: 1.0965x; 1.0965x over previous
//
#include <hip/hip_runtime.h>
#include <cstddef>

#define NB 8
#define NT 2048
#define NE 256
#define NH 4
#define ND 64
#define NP 8

typedef short bf16x8 __attribute__((ext_vector_type(8)));
typedef float f32x4 __attribute__((ext_vector_type(4)));

__device__ __forceinline__ unsigned short f2bf(float f) {
  unsigned u = __builtin_bit_cast(unsigned, f);
  u += 0x7fffu + ((u >> 16) & 1u);          // RNE
  return (unsigned short)(u >> 16);
}
__device__ __forceinline__ float bf2f(unsigned short h) {
  unsigned u = ((unsigned)h) << 16;
  return __builtin_bit_cast(float, u);
}
// packed hi/lo split of a float pair (integer-only)
__device__ __forceinline__ void split2(float a, float b, unsigned& hi, unsigned& lo) {
  const unsigned short ha = f2bf(a), hb = f2bf(b);
  hi = (unsigned)ha | ((unsigned)hb << 16);
  const unsigned short la = f2bf(a - bf2f(ha));
  const unsigned short lb = f2bf(b - bf2f(hb));
  lo = (unsigned)la | ((unsigned)lb << 16);
}
__device__ __forceinline__ void gld16(const void* g, void* l) {
  __builtin_amdgcn_global_load_lds((const __attribute__((address_space(1))) unsigned*)g,
                                   (__attribute__((address_space(3))) unsigned*)l, 16, 0, 0);
}

// q-prescale: 1/8 (attn scale) * log2(e) (exp2 domain for softmax)
#define QSC 0.180336880111120419f

// ---------------- setup: wqk split(+q prescale), w_in split, prep(uv->wqkv rows), zero --
__global__ __launch_bounds__(256) void setup_kernel(
    const float* __restrict__ w_in, const float* __restrict__ w_q,
    const float* __restrict__ w_k, const float* __restrict__ b_q,
    const float* __restrict__ b_k, const float* __restrict__ w_o,
    const float* __restrict__ b_o, const float* __restrict__ w_bd,
    const float* __restrict__ b_bd, const float* __restrict__ w_v,
    const float* __restrict__ b_v,
    unsigned short* __restrict__ wihi, unsigned short* __restrict__ wilo,
    unsigned short* __restrict__ wqkvhi, unsigned short* __restrict__ wqkvlo,
    float* __restrict__ bqk, float* __restrict__ consts, float* __restrict__ psum)
{
  __shared__ float wbd_s[NE];
  __shared__ float u_s[NE];
  const int b = blockIdx.x, tid = threadIdx.x;
  if (b < 512) {
    const int i = b * 256 + tid;                         // [0,131072)
    const float v = (i < 65536) ? w_q[i] * QSC : w_k[i - 65536];
    const unsigned short h = f2bf(v);
    wqkvhi[i] = h;
    wqkvlo[i] = f2bf(v - bf2f(h));
    if (i < 512) bqk[i] = (i < 256) ? b_q[i] * QSC : b_k[i - 256];
  } else if (b < 576) {
    const int i = (b - 512) * 256 + tid;                 // float4 idx [0,16384)
    const float4 v = *(const float4*)(w_in + (size_t)i * 4);
    const float vv[4] = {v.x, v.y, v.z, v.w};
    unsigned short h4[4], l4[4];
    #pragma unroll
    for (int j = 0; j < 4; ++j) {
      h4[j] = f2bf(vv[j]);
      l4[j] = f2bf(vv[j] - bf2f(h4[j]));
    }
    *(ushort2*)(wihi + (size_t)i * 4)     = make_ushort2(h4[0], h4[1]);
    *(ushort2*)(wihi + (size_t)i * 4 + 2) = make_ushort2(h4[2], h4[3]);
    *(ushort2*)(wilo + (size_t)i * 4)     = make_ushort2(l4[0], l4[1]);
    *(ushort2*)(wilo + (size_t)i * 4 + 2) = make_ushort2(l4[2], l4[3]);
  } else if (b == 576) {
    wbd_s[tid] = w_bd[tid];
    __syncthreads();
    float a = 0.f;
    for (int j = 0; j < NE; ++j) a = fmaf(wbd_s[j], w_o[j * NE + tid], a);
    u_s[tid] = a;
    __syncthreads();
    #pragma unroll
    for (int hh = 0; hh < NH; ++hh) {
      float a2 = 0.f;
      for (int d = 0; d < ND; ++d)
        a2 = fmaf(u_s[hh * ND + d], w_v[(size_t)(hh * ND + d) * NE + tid], a2);
      const unsigned short hb = f2bf(a2);
      wqkvhi[(512 + hh) * 256 + tid] = hb;
      wqkvlo[(512 + hh) * 256 + tid] = f2bf(a2 - bf2f(hb));
    }
    for (int i = tid; i < 60 * 256; i += 256) {          // zero-pad rows 516..575
      wqkvhi[516 * 256 + i] = 0;
      wqkvlo[516 * 256 + i] = 0;
    }
    if (tid == 0) {
      float cc = 0.f;
      for (int j = 0; j < NE; ++j) cc = fmaf(wbd_s[j], b_o[j], cc);
      consts[0] = cc + b_bd[0];
    }
    if (tid < 4) {
      float cv = 0.f;
      for (int d = 0; d < ND; ++d) cv = fmaf(u_s[tid * ND + d], b_v[tid * ND + d], cv);
      bqk[512 + tid] = cv;
    } else if (tid < 64) {
      bqk[512 + tid] = 0.f;
    }
  } else {
    for (int i = tid; i < NB * NP * NE; i += 256) psum[i] = 0.f;
  }
}

// ---------------- hgemm v2: LDS-staged, dbuf, gld16. h = x @ w_in^T + b_in -------------
__global__ __launch_bounds__(256) void hgemm_kernel(
    const float* __restrict__ x,
    const unsigned short* __restrict__ wihi, const unsigned short* __restrict__ wilo,
    const float* __restrict__ b_in,
    unsigned short* __restrict__ hhi, unsigned short* __restrict__ hlo)
{
  __shared__ __align__(16) char sm[2][24576];
  const int tid = threadIdx.x;
  const int wave = tid >> 6, lane = tid & 63;
  const int lr = lane & 15, lg = lane >> 4;
  const int wm = wave >> 1, wn = wave & 1;
  const int bid = blockIdx.x;
  const int idx = bid >> 3;
  const int m0 = ((bid & 7) * 16 + (idx >> 2)) * 128;
  const int n0 = (idx & 3) * 64;

  const float* aSrc[4];
  #pragma unroll
  for (int c = 0; c < 4; ++c) {
    const int L = c * 4096 + tid * 16;
    const int row = L >> 7, w = (L >> 4) & 7;
    aSrc[c] = x + (size_t)(m0 + row) * 256 + (w ^ (row & 7)) * 4;
  }
  const unsigned short* wSrc[2];
  #pragma unroll
  for (int c = 0; c < 2; ++c) {
    const int L = c * 4096 + tid * 16;
    const int half = (L >> 12) & 1;
    const int Lh = L & 4095;
    const int col = Lh >> 6, w = (Lh >> 4) & 3;
    wSrc[c] = (half ? wilo : wihi) + (size_t)(n0 + col) * 256 + (w ^ ((col >> 1) & 3)) * 8;
  }
  int aoff[4][2], woff[2];
  #pragma unroll
  for (int s = 0; s < 4; ++s) {
    const int row = wm * 64 + s * 16 + lr;
    const int b0 = row * 128 + lg * 32;
    const int f = (row & 7) << 4;
    aoff[s][0] = b0 ^ f;
    aoff[s][1] = (b0 + 16) ^ f;
  }
  #pragma unroll
  for (int ns = 0; ns < 2; ++ns) {
    const int col = wn * 32 + ns * 16 + lr;
    woff[ns] = (col * 64 + lg * 16) ^ (((col >> 1) & 3) << 4);
  }

  f32x4 acc[4][2];
  #pragma unroll
  for (int s = 0; s < 4; ++s)
    #pragma unroll
    for (int ns = 0; ns < 2; ++ns) acc[s][ns] = (f32x4){0.f, 0.f, 0.f, 0.f};

  {
    char* lb = sm[0];
    #pragma unroll
    for (int c = 0; c < 4; ++c) gld16(aSrc[c], lb + c * 4096 + wave * 1024);
    #pragma unroll
    for (int c = 0; c < 2; ++c) gld16(wSrc[c], lb + 16384 + c * 4096 + wave * 1024);
  }

  for (int kt = 0; kt < 8; ++kt) {
    __syncthreads();
    if (kt < 7) {
      char* nb = sm[(kt + 1) & 1];
      #pragma unroll
      for (int c = 0; c < 4; ++c) gld16(aSrc[c] + (kt + 1) * 32, nb + c * 4096 + wave * 1024);
      #pragma unroll
      for (int c = 0; c < 2; ++c) gld16(wSrc[c] + (kt + 1) * 32, nb + 16384 + c * 4096 + wave * 1024);
    }
    const char* lb = sm[kt & 1];
    bf16x8 ah[4], al[4], wh[2], wl[2];
    #pragma unroll
    for (int s = 0; s < 4; ++s) {
      const f32x4 p0 = *(const f32x4*)(lb + aoff[s][0]);
      const f32x4 p1 = *(const f32x4*)(lb + aoff[s][1]);
      unsigned h0, h1, h2, h3, l0, l1, l2, l3;
      split2(p0[0], p0[1], h0, l0);
      split2(p0[2], p0[3], h1, l1);
      split2(p1[0], p1[1], h2, l2);
      split2(p1[2], p1[3], h3, l3);
      const uint4 hu = make_uint4(h0, h1, h2, h3);
      const uint4 lu = make_uint4(l0, l1, l2, l3);
      ah[s] = __builtin_bit_cast(bf16x8, hu);
      al[s] = __builtin_bit_cast(bf16x8, lu);
    }
    #pragma unroll
    for (int ns = 0; ns < 2; ++ns) {
      wh[ns] = *(const bf16x8*)(lb + 16384 + woff[ns]);
      wl[ns] = *(const bf16x8*)(lb + 20480 + woff[ns]);
    }
    #pragma unroll
    for (int s = 0; s < 4; ++s)
      #pragma unroll
      for (int ns = 0; ns < 2; ++ns) {
        acc[s][ns] = __builtin_amdgcn_mfma_f32_16x16x32_bf16(ah[s], wh[ns], acc[s][ns], 0, 0, 0);
        acc[s][ns] = __builtin_amdgcn_mfma_f32_16x16x32_bf16(ah[s], wl[ns], acc[s][ns], 0, 0, 0);
        acc[s][ns] = __builtin_amdgcn_mfma_f32_16x16x32_bf16(al[s], wh[ns], acc[s][ns], 0, 0, 0);
      }
  }
  #pragma unroll
  for (int s = 0; s < 4; ++s)
    #pragma unroll
    for (int ns = 0; ns < 2; ++ns)
      #pragma unroll
      for (int reg = 0; reg < 4; ++reg) {
        const int row = m0 + wm * 64 + s * 16 + lg * 4 + reg;
        const int col = n0 + wn * 32 + ns * 16 + lr;
        const float v = acc[s][ns][reg] + b_in[col];
        const size_t i2 = (size_t)row * 256 + col;
        const unsigned short hb = f2bf(v);
        hhi[i2] = hb;
        hlo[i2] = f2bf(v - bf2f(hb));
      }
}

// ---------------- qkv-gemm v2: LDS-staged dbuf. [q*QSC|k|vu] = h @ wqkv^T + bqk --------
__global__ __launch_bounds__(256) void qkvgemm_kernel(
    const unsigned short* __restrict__ Ahi, const unsigned short* __restrict__ Alo,
    const unsigned short* __restrict__ Whi, const unsigned short* __restrict__ Wlo,
    const float* __restrict__ bias,
    unsigned short* __restrict__ Qhi, unsigned short* __restrict__ Qlo,
    unsigned short* __restrict__ Khi, unsigned short* __restrict__ Klo,
    float* __restrict__ vubuf)
{
  __shared__ __align__(16) char sm[2][24576];
  const int tid = threadIdx.x;
  const int wave = tid >> 6, lane = tid & 63;
  const int lr = lane & 15, lg = lane >> 4;
  const int wm = wave >> 1, wn = wave & 1;
  const int bid = blockIdx.x;
  const int idx = bid >> 3;                     // 0..143
  const int m0 = ((bid & 7) * 16 + idx / 9) * 128;
  const int n0 = (idx % 9) * 64;

  const unsigned short* aSrc[4];
  #pragma unroll
  for (int c = 0; c < 4; ++c) {
    const int L = c * 4096 + tid * 16;
    const int half = L >> 13;
    const int Lh = L & 8191;
    const int row = Lh >> 6, w = (Lh >> 4) & 3;
    aSrc[c] = (half ? Alo : Ahi) + (size_t)(m0 + row) * 256 + (w ^ ((row >> 1) & 3)) * 8;
  }
  const unsigned short* wSrc[2];
  #pragma unroll
  for (int c = 0; c < 2; ++c) {
    const int L = c * 4096 + tid * 16;
    const int half = (L >> 12) & 1;
    const int Lh = L & 4095;
    const int col = Lh >> 6, w = (Lh >> 4) & 3;
    wSrc[c] = (half ? Wlo : Whi) + (size_t)(n0 + col) * 256 + (w ^ ((col >> 1) & 3)) * 8;
  }
  int aoff[4], woff[2];
  #pragma unroll
  for (int s = 0; s < 4; ++s) {
    const int row = wm * 64 + s * 16 + lr;
    aoff[s] = (row * 64 + lg * 16) ^ (((row >> 1) & 3) << 4);
  }
  #pragma unroll
  for (int ns = 0; ns < 2; ++ns) {
    const int col = wn * 32 + ns * 16 + lr;
    woff[ns] = (col * 64 + lg * 16) ^ (((col >> 1) & 3) << 4);
  }

  f32x4 acc[4][2];
  #pragma unroll
  for (int s = 0; s < 4; ++s)
    #pragma unroll
    for (int ns = 0; ns < 2; ++ns) acc[s][ns] = (f32x4){0.f, 0.f, 0.f, 0.f};

  {
    char* lb = sm[0];
    #pragma unroll
    for (int c = 0; c < 4; ++c) gld16(aSrc[c], lb + c * 4096 + wave * 1024);
    #pragma unroll
    for (int c = 0; c < 2; ++c) gld16(wSrc[c], lb + 16384 + c * 4096 + wave * 1024);
  }

  for (int kt = 0; kt < 8; ++kt) {
    __syncthreads();
    if (kt < 7) {
      char* nb = sm[(kt + 1) & 1];
      #pragma unroll
      for (int c = 0; c < 4; ++c) gld16(aSrc[c] + (kt + 1) * 32, nb + c * 4096 + wave * 1024);
      #pragma unroll
      for (int c = 0; c < 2; ++c) gld16(wSrc[c] + (kt + 1) * 32, nb + 16384 + c * 4096 + wave * 1024);
    }
    const char* lb = sm[kt & 1];
    bf16x8 ah[4], al[4], wh[2], wl[2];
    #pragma unroll
    for (int s = 0; s < 4; ++s) {
      ah[s] = *(const bf16x8*)(lb + aoff[s]);
      al[s] = *(const bf16x8*)(lb + 8192 + aoff[s]);
    }
    #pragma unroll
    for (int ns = 0; ns < 2; ++ns) {
      wh[ns] = *(const bf16x8*)(lb + 16384 + woff[ns]);
      wl[ns] = *(const bf16x8*)(lb + 20480 + woff[ns]);
    }
    #pragma unroll
    for (int s = 0; s < 4; ++s)
      #pragma unroll
      for (int ns = 0; ns < 2; ++ns) {
        acc[s][ns] = __builtin_amdgcn_mfma_f32_16x16x32_bf16(ah[s], wh[ns], acc[s][ns], 0, 0, 0);
        acc[s][ns] = __builtin_amdgcn_mfma_f32_16x16x32_bf16(ah[s], wl[ns], acc[s][ns], 0, 0, 0);
        acc[s][ns] = __builtin_amdgcn_mfma_f32_16x16x32_bf16(al[s], wh[ns], acc[s][ns], 0, 0, 0);
      }
  }
  #pragma unroll
  for (int s = 0; s < 4; ++s)
    #pragma unroll
    for (int ns = 0; ns < 2; ++ns)
      #pragma unroll
      for (int reg = 0; reg < 4; ++reg) {
        const int row = m0 + wm * 64 + s * 16 + lg * 4 + reg;
        const int col = n0 + wn * 32 + ns * 16 + lr;
        const float v = acc[s][ns][reg] + bias[col];
        const int b = row >> 11, t = row & 2047;
        if (col < 512) {
          const int c = col & 255;
          const int head = c >> 6, d = c & 63;
          const size_t i2 = (((size_t)(b * NH + head)) * NT + t) * ND + d;
          const unsigned short hb = f2bf(v);
          if (col < 256) { Qhi[i2] = hb; Qlo[i2] = f2bf(v - bf2f(hb)); }
          else           { Khi[i2] = hb; Klo[i2] = f2bf(v - bf2f(hb)); }
        } else if (col < 516) {
          vubuf[((size_t)(b * NH + (col - 512))) * NT + t] = v;
        }
      }
}

// ---------------- attention v8: stage-once + WAVE-STAGGERED tile order -----------------
// split-K x8: 2048 blocks; block = 256 q x 256 k (4 tiles staged upfront, 1 barrier).
// 512 thr / 8 waves; wave = 32 q-rows. Wave w starts at tile (w&3) -> waves anti-phase,
// so one wave's exp/fma overlaps another's MFMA on the same SIMD (m114 co-issue).
__global__ __launch_bounds__(512) void attn_kernel8(
    const unsigned short* __restrict__ qhi, const unsigned short* __restrict__ qlo,
    const unsigned short* __restrict__ khi, const unsigned short* __restrict__ klo,
    const float* __restrict__ vu, float2* __restrict__ part2)
{
  __shared__ __align__(16) char kbuf[4][16384];   // 4 tiles x [hi 8KB | lo 8KB], swizzled
  __shared__ float vu_s[256];
  const int tid = threadIdx.x;
  const int wave = tid >> 6, lane = tid & 63;
  const int lr = lane & 15, lg = lane >> 4;
  // XCD-aware: bid&7 -> XCD; each XCD covers 4 contiguous bh (K/Q L2-resident)
  const int bid = blockIdx.x;                     // 0..2047
  const int idx = bid >> 3;                       // 0..255
  const int bh = (bid & 7) * 4 + (idx >> 6);
  const int rem = idx & 63;
  const int qt = rem >> 3, kh = rem & 7;
  const size_t base = (size_t)bh * NT * ND;
  const int qrow0 = qt * 256 + wave * 32;
  const int krow0 = kh * 256;

  if (tid < 256) vu_s[tid] = vu[(size_t)bh * NT + krow0 + tid];

  // Q fragments in regs: [m-subtile][d-slice][hi/lo]
  bf16x8 qf[2][2][2];
  #pragma unroll
  for (int s = 0; s < 2; ++s)
    #pragma unroll
    for (int ds = 0; ds < 2; ++ds) {
      const size_t off = base + (size_t)(qrow0 + s * 16 + lr) * ND + ds * 32 + lg * 8;
      qf[s][ds][0] = *(const bf16x8*)(qhi + off);
      qf[s][ds][1] = *(const bf16x8*)(qlo + off);
    }

  // pre-swizzled global source offset (involution; LDS dest linear per lane)
  const int so = (tid * 16) ^ (((tid >> 3) & 7) << 4);
  int ro0[4], ro1[4];
  #pragma unroll
  for (int ns = 0; ns < 4; ++ns) {
    const int r = ns * 16 + lr;
    const int sw = (r & 7) << 4;
    const int ob = r * 128 + lg * 16;
    ro0[ns] = ob ^ sw;
    ro1[ns] = (ob + 64) ^ sw;
  }
  const char* srcH = (const char*)(khi + base + (size_t)krow0 * ND);
  const char* srcL = (const char*)(klo + base + (size_t)krow0 * ND);
  // stage ALL 4 tiles via async DMA, one barrier total
  #pragma unroll
  for (int t = 0; t < 4; ++t) {
    gld16(srcH + t * 8192 + so, &kbuf[t][wave * 1024]);
    gld16(srcL + t * 8192 + so, &kbuf[t][8192 + wave * 1024]);
  }
  __syncthreads();                                // drains all gld16; only barrier

  float l[8], sv[8];
  #pragma unroll
  for (int i = 0; i < 8; ++i) { l[i] = 0.f; sv[i] = 0.f; }
  const f32x4 Z = (f32x4){0.f, 0.f, 0.f, 0.f};    // persistent zero C-operand

  #pragma unroll
  for (int it = 0; it < 4; ++it) {
    const int kt = (it + wave) & 3;               // wave-staggered tile order
    const char* kb = (const char*)kbuf[kt];
    f32x4 acc[2][4];
    float vuv[4];
    __builtin_amdgcn_s_setprio(1);
    #pragma unroll
    for (int ns = 0; ns < 4; ++ns) {
      const bf16x8 kh0 = *(const bf16x8*)(kb + ro0[ns]);
      const bf16x8 kh1 = *(const bf16x8*)(kb + ro1[ns]);
      const bf16x8 kl0 = *(const bf16x8*)(kb + 8192 + ro0[ns]);
      const bf16x8 kl1 = *(const bf16x8*)(kb + 8192 + ro1[ns]);
      vuv[ns] = vu_s[kt * 64 + ns * 16 + lr];
      #pragma unroll
      for (int s = 0; s < 2; ++s) {
        acc[s][ns] = __builtin_amdgcn_mfma_f32_16x16x32_bf16(qf[s][0][0], kh0, Z, 0, 0, 0);
        acc[s][ns] = __builtin_amdgcn_mfma_f32_16x16x32_bf16(qf[s][0][0], kl0, acc[s][ns], 0, 0, 0);
        acc[s][ns] = __builtin_amdgcn_mfma_f32_16x16x32_bf16(qf[s][0][1], kh0, acc[s][ns], 0, 0, 0);
        acc[s][ns] = __builtin_amdgcn_mfma_f32_16x16x32_bf16(qf[s][1][0], kh1, acc[s][ns], 0, 0, 0);
        acc[s][ns] = __builtin_amdgcn_mfma_f32_16x16x32_bf16(qf[s][1][0], kl1, acc[s][ns], 0, 0, 0);
        acc[s][ns] = __builtin_amdgcn_mfma_f32_16x16x32_bf16(qf[s][1][1], kh1, acc[s][ns], 0, 0, 0);
      }
    }
    __builtin_amdgcn_s_setprio(0);
    // exp2-domain softmax accumulation (scores already in log2 units via QSC)
    #pragma unroll
    for (int s = 0; s < 2; ++s)
      #pragma unroll
      for (int reg = 0; reg < 4; ++reg) {
        const int ri = s * 4 + reg;
        #pragma unroll
        for (int ns = 0; ns < 4; ++ns) {
          const float e = __builtin_amdgcn_exp2f(acc[s][ns][reg]);
          l[ri] += e;
          sv[ri] = fmaf(e, vuv[ns], sv[ri]);
        }
      }
  }
  // reduce partial l/sv across the 16-lane column group
  #pragma unroll
  for (int ri = 0; ri < 8; ++ri) {
    #pragma unroll
    for (int off = 1; off < 16; off <<= 1) {
      l[ri]  += __shfl_xor(l[ri],  off, 16);
      sv[ri] += __shfl_xor(sv[ri], off, 16);
    }
  }
  if (lr == 0) {
    #pragma unroll
    for (int s = 0; s < 2; ++s)
      #pragma unroll
      for (int reg = 0; reg < 4; ++reg) {
        const int row = qrow0 + s * 16 + lg * 4 + reg;
        part2[(((size_t)bh * NT + row) << 3) + kh] = make_float2(l[s * 4 + reg], sv[s * 4 + reg]);
      }
  }
}

// ---------------- combine: reduce split-K x8 partials -> bs = sigmoid(logit) -----------
// grid 64 x 256: one thread per (b,t).
__global__ __launch_bounds__(256) void combine_kernel(
    const float4* __restrict__ part4, const float* __restrict__ consts,
    float* __restrict__ bs)
{
  const int gid = blockIdx.x * 256 + threadIdx.x;    // 0..16383
  const int b = gid >> 11, t = gid & 2047;
  float logit = consts[0];
  #pragma unroll
  for (int hh = 0; hh < NH; ++hh) {
    const size_t p0 = ((size_t)((b * NH + hh) * NT) + t) * 4;   // 4 float4 = 8 {l,sv}
    float lsum = 0.f, ssum = 0.f;
    #pragma unroll
    for (int q = 0; q < 4; ++q) {
      const float4 p = part4[p0 + q];
      lsum += p.x + p.z;
      ssum += p.y + p.w;
    }
    logit += ssum / lsum;
  }
  bs[gid] = 1.f / (1.f + expf(-logit));
}

// ---------------- boundary: cumsum bs, pid, counts (one block per batch) ---------------
__global__ __launch_bounds__(256) void boundary_kernel(
    const float* __restrict__ bs, int* __restrict__ pid, int* __restrict__ counts)
{
  const int b = blockIdx.x, tid = threadIdx.x;
  __shared__ float partial[256];
  __shared__ int cnt_s[8];
  float v[8];
  float run = 0.f;
  const float4 b0 = *(const float4*)(bs + b * NT + tid * 8);
  const float4 b1 = *(const float4*)(bs + b * NT + tid * 8 + 4);
  const float bv[8] = {b0.x, b0.y, b0.z, b0.w, b1.x, b1.y, b1.z, b1.w};
  #pragma unroll
  for (int i = 0; i < 8; ++i) { run += bv[i]; v[i] = run; }
  float x = run;
  partial[tid] = x;
  __syncthreads();
  for (int off = 1; off < 256; off <<= 1) {
    const float y = (tid >= off) ? partial[tid - off] : 0.f;
    __syncthreads();
    x += y;
    partial[tid] = x;
    __syncthreads();
  }
  const float total = partial[255];
  if (tid < 8) cnt_s[tid] = 0;
  __syncthreads();
  const float denom = fmaxf(total, 1e-6f);
  const float excl = x - run;
  #pragma unroll
  for (int i = 0; i < 8; ++i) {
    const float norm = (excl + v[i]) / denom;
    int pp = (int)(norm * 8.f);
    pp = pp > 7 ? 7 : pp;
    pid[b * NT + tid * 8 + i] = pp;
    atomicAdd(&cnt_s[pp], 1);
  }
  __syncthreads();
  if (tid < 8) counts[b * 8 + tid] = cnt_s[tid];
}

// ---------------- pool hhi into patch sums (branchless 8-way select) -------------------
__global__ __launch_bounds__(256) void pool_kernel(
    const unsigned short* __restrict__ hhi, const int* __restrict__ pid,
    float* __restrict__ psum)
{
  const int b = blockIdx.x >> 4, chunk = blockIdx.x & 15;
  const int tid = threadIdx.x;
  __shared__ int pid_s[128];
  const int t0 = chunk * 128;
  if (tid < 128) pid_s[tid] = pid[b * NT + t0 + tid];
  __syncthreads();
  float acc[8] = {};
  for (int tok = 0; tok < 128; ++tok) {
    const float val = bf2f(hhi[((size_t)b * NT + t0 + tok) * NE + tid]);
    const int p = pid_s[tok];
    #pragma unroll
    for (int pp = 0; pp < 8; ++pp) acc[pp] += (p == pp) ? val : 0.f;
  }
  #pragma unroll
  for (int pp = 0; pp < 8; ++pp)
    atomicAdd(&psum[((size_t)b * NP + pp) * NE + tid], acc[pp]);
}

// ---------------- final: out = (psum/count) @ w_pr^T + b_pr ---------------------------
__global__ __launch_bounds__(256) void final_kernel(
    const float* __restrict__ psum, const int* __restrict__ counts,
    const float* __restrict__ w_pr, const float* __restrict__ b_pr, float* __restrict__ out)
{
  const int bp = blockIdx.x;
  const int tid = threadIdx.x;
  __shared__ float pe[NE];
  const float cnt = fmaxf((float)counts[bp], 1.f);
  pe[tid] = psum[(size_t)bp * NE + tid] / cnt;
  __syncthreads();
  float acc = 0.f;
  for (int e = 0; e < NE; ++e) acc = fmaf(pe[e], w_pr[(size_t)tid * NE + e], acc);
  out[(size_t)bp * NE + tid] = acc + b_pr[tid];
}

extern "C" void kernel_launch(void* const* d_in, const int* in_sizes, int n_in,
                              void* d_out, int out_size, void* d_ws, size_t ws_size,
                              hipStream_t stream) {
  (void)in_sizes; (void)n_in; (void)out_size; (void)ws_size;
  const float* x    = (const float*)d_in[0];
  const float* w_in = (const float*)d_in[1];
  const float* b_in = (const float*)d_in[2];
  const float* w_q  = (const float*)d_in[3];
  const float* b_q  = (const float*)d_in[4];
  const float* w_k  = (const float*)d_in[5];
  const float* b_k  = (const float*)d_in[6];
  const float* w_v  = (const float*)d_in[7];
  const float* b_v  = (const float*)d_in[8];
  const float* w_o  = (const float*)d_in[9];
  const float* b_o  = (const float*)d_in[10];
  const float* w_bd = (const float*)d_in[11];
  const float* b_bd = (const float*)d_in[12];
  const float* w_pr = (const float*)d_in[13];
  const float* b_pr = (const float*)d_in[14];
  float* out = (float*)d_out;

  const size_t M = (size_t)NB * NT;                       // 16384
  unsigned short* hhi = (unsigned short*)d_ws;            // M*NE u16 each
  unsigned short* hlo = hhi + M * NE;
  unsigned short* qhi = hlo + M * NE;
  unsigned short* qlo = qhi + M * NE;
  unsigned short* khi = qlo + M * NE;
  unsigned short* klo = khi + M * NE;
  unsigned short* wihi = klo + M * NE;                    // 65,536 each
  unsigned short* wilo = wihi + 65536;
  unsigned short* wqkvhi = wilo + 65536;                  // 147,456 each (576x256)
  unsigned short* wqkvlo = wqkvhi + 147456;
  float* bqk    = (float*)(wqkvlo + 147456);              // 576
  float* vubuf  = bqk + 576;                              // 65,536 [B,H,T]
  float* part   = vubuf + 65536;                          // 1,048,576 [bh][t][kh8][{l,sv}]
  float* bsbuf  = part + 1048576;                         // 16,384
  float* consts = bsbuf + 16384;                          // 8
  float* psum   = consts + 8;                             // 16,384
  int*   pid    = (int*)(psum + 16384);                   // 16,384
  int*   counts = pid + 16384;                            // 64

  setup_kernel<<<578, 256, 0, stream>>>(w_in, w_q, w_k, b_q, b_k, w_o, b_o,
      w_bd, b_bd, w_v, b_v, wihi, wilo, wqkvhi, wqkvlo, bqk, consts, psum);
  hgemm_kernel<<<512, 256, 0, stream>>>(x, wihi, wilo, b_in, hhi, hlo);
  qkvgemm_kernel<<<1152, 256, 0, stream>>>(hhi, hlo, wqkvhi, wqkvlo, bqk,
      qhi, qlo, khi, klo, vubuf);
  attn_kernel8<<<2048, 512, 0, stream>>>(qhi, qlo, khi, klo, vubuf, (float2*)part);
  combine_kernel<<<64, 256, 0, stream>>>((const float4*)part, consts, bsbuf);
  boundary_kernel<<<8, 256, 0, stream>>>(bsbuf, pid, counts);
  pool_kernel<<<128, 256, 0, stream>>>(hhi, pid, psum);
  final_kernel<<<64, 256, 0, stream>>>(psum, counts, w_pr, b_pr, out);
}